// Round 1
// baseline (191.076 us; speedup 1.0000x reference)
//
#include <hip/hip_runtime.h>
#include <math.h>

#define HIDDEN 768

// -ln(10000)/768 and -ln(10000)/256
#define K768 (-0.011992630692677323f)
#define K256 (-0.035977892078031970f)
// exp(256*K768) = 10000^(-1/3), exp(512*K768) = 10000^(-2/3)
#define C256 (0.04641588833612779f)
#define C512 (0.002154434690031884f)

#define ROWS 4   // rows per wave, all gathers issued up-front

typedef float nfloat4 __attribute__((ext_vector_type(4)));  // native vec for NT stores

__global__ __launch_bounds__(256, 4) void emb_ln_kernel(
    const int*   __restrict__ input_ids,    // B*S
    const int*   __restrict__ tok_struct,   // B*S*3
    const int*   __restrict__ token_type,   // B*S
    const float* __restrict__ word_emb,     // VOCAB*768
    const float* __restrict__ type_emb,     // 2*768
    const float* __restrict__ ln_w,         // 768
    const float* __restrict__ ln_b,         // 768
    float*       __restrict__ out,          // B*S*768
    int S, int BS)
{
    const int wave = threadIdx.x >> 6;
    const int lane = threadIdx.x & 63;
    const int gw   = blockIdx.x * 4 + wave;   // global wave id
    const int NW   = gridDim.x * 4;           // total waves

    const int h0 = lane * 4;   // lane owns h = h0 + 256*j + c

    // per-lane constants, computed once per wave
    const float d0 = __expf((float)h0 * K256);
    const float d1 = __expf((float)(h0 + 2) * K256);
    const float e0 = __expf((float)h0 * K768);
    const float e2 = __expf((float)(h0 + 2) * K768);

    // ln params cached in registers (used only in epilogue).
    // type_emb is NOT cached: 12 KB working set is L1-resident, reloaded per row
    // to free 24 VGPRs for the 4-deep gather buffers.
    float4 g[3], bb[3];
    {
        const float4* wv = (const float4*)ln_w;
        const float4* bv = (const float4*)ln_b;
#pragma unroll
        for (int j = 0; j < 3; ++j) {
            g[j]  = wv[lane + 64 * j];
            bb[j] = bv[lane + 64 * j];
        }
    }

    const int r0 = gw;
    if (r0 >= BS) return;

    // ---- load ALL row indices first (breaks the index->gather serial chain) ----
    int id[ROWS], tt[ROWS], pp[ROWS];
#pragma unroll
    for (int i = 0; i < ROWS; ++i) {
        const int rr = r0 + i * NW;
        const int rc = (rr < BS) ? rr : r0;   // clamp OOB to a valid row (data unused)
        id[i] = input_ids[rc];
        tt[i] = token_type[rc];
        pp[i] = tok_struct[3 * rc];
    }

    // ---- issue ALL word_emb gathers up-front: 12 KB/wave in flight ----
    float4 w[ROWS][3];
#pragma unroll
    for (int i = 0; i < ROWS; ++i) {
        const float4* wrow = (const float4*)(word_emb + (size_t)id[i] * HIDDEN);
#pragma unroll
        for (int j = 0; j < 3; ++j) w[i][j] = wrow[lane + 64 * j];
    }

    const float inv_n = 1.0f / (float)HIDDEN;

    // ---- compute rows in order as their data arrives ----
#pragma unroll
    for (int i = 0; i < ROWS; ++i) {
        const int r = r0 + i * NW;
        if (r >= BS) break;   // rows are increasing in i

        const float fpp = (float)pp[i];
        const float hs0 = __sinf(fpp * d0);
        const float hs1 = __cosf(fpp * d0);
        const float hs2 = __sinf(fpp * d1);
        const float hs3 = __cosf(fpp * d1);

        const float fs = (float)(r & (S - 1));
        const float4* ty = (const float4*)(type_emb + tt[i] * HIDDEN);

        float v[12];
#pragma unroll
        for (int j = 0; j < 3; ++j) {
            const float scale = (j == 0) ? 1.0f : (j == 1 ? C256 : C512);
            const float a0 = fs * (e0 * scale);
            const float a1 = fs * (e2 * scale);
            const float4 t = ty[lane + 64 * j];   // L1-hit
            v[4 * j + 0] = w[i][j].x + t.x + __sinf(a0) + hs0;
            v[4 * j + 1] = w[i][j].y + t.y + __cosf(a0) + hs1;
            v[4 * j + 2] = w[i][j].z + t.z + __sinf(a1) + hs2;
            v[4 * j + 3] = w[i][j].w + t.w + __cosf(a1) + hs3;
        }

        float s1 = 0.0f, s2 = 0.0f;
#pragma unroll
        for (int k = 0; k < 12; ++k) {
            s1 += v[k];
            s2 = fmaf(v[k], v[k], s2);
        }
#pragma unroll
        for (int off = 1; off < 64; off <<= 1) {
            s1 += __shfl_xor(s1, off, 64);
            s2 += __shfl_xor(s2, off, 64);
        }

        const float mu = s1 * inv_n;
        const float rstd = rsqrtf(fmaxf(s2 * inv_n - mu * mu, 0.0f) + 1e-12f);

        nfloat4* orow = (nfloat4*)(out + (size_t)r * HIDDEN);
#pragma unroll
        for (int j = 0; j < 3; ++j) {
            nfloat4 rr;
            rr.x = (v[4 * j + 0] - mu) * rstd * g[j].x + bb[j].x;
            rr.y = (v[4 * j + 1] - mu) * rstd * g[j].y + bb[j].y;
            rr.z = (v[4 * j + 2] - mu) * rstd * g[j].z + bb[j].z;
            rr.w = (v[4 * j + 3] - mu) * rstd * g[j].w + bb[j].w;
            __builtin_nontemporal_store(rr, &orow[lane + 64 * j]);
        }
    }
}

extern "C" void kernel_launch(void* const* d_in, const int* in_sizes, int n_in,
                              void* d_out, int out_size, void* d_ws, size_t ws_size,
                              hipStream_t stream) {
    const int*   input_ids  = (const int*)  d_in[0];
    const int*   tok_struct = (const int*)  d_in[1];
    // d_in[2] = sent_struct_vec (unused by the reference output)
    const int*   token_type = (const int*)  d_in[3];
    const float* word_emb   = (const float*)d_in[4];
    const float* type_emb   = (const float*)d_in[5];
    const float* ln_w       = (const float*)d_in[6];
    const float* ln_b       = (const float*)d_in[7];
    float* out = (float*)d_out;

    const int BS = in_sizes[0];          // B * S
    const int B  = in_sizes[2] / 128;    // sent_struct_vec is B*64*2
    const int S  = BS / B;               // 4096

    // Each wave owns ROWS rows (strided by NW); all gathers issued up-front.
    // blocks*4 waves * ROWS rows >= BS
    int blocks = (BS + 4 * ROWS - 1) / (4 * ROWS);   // 2048 for BS=32768
    emb_ln_kernel<<<blocks, 256, 0, stream>>>(input_ids, tok_struct, token_type,
                                              word_emb, type_emb, ln_w, ln_b,
                                              out, S, BS);
}